// Round 10
// baseline (650.581 us; speedup 1.0000x reference)
//
#include <hip/hip_runtime.h>
#include <hip/hip_bf16.h>
#include <cstdint>
#include <cstddef>

#define NN 25000
#define NE 400000
#define NFD 30
#define EFD 10
#define H 40
#define T 5
#define FO 8
#define LAYERS 2
#define TF 200          // T*F
#define BASE_W 800      // T*160
#define PSTR 52         // padded row stride for P1/P2
#define WS_PAD 532      // padded LDS row stride (floats) for post weights
#define ABN 32          // nodes per block in k_ab (32 -> 782 blocks, occupancy-matched)
#define REC 12          // floats per CSR edge record [ea0..9, src, eid]
#define EPSV 1e-5f

// ---------- degree histogram ----------
__global__ __launch_bounds__(256) void k_deg(const int* __restrict__ dst, int* __restrict__ cnt) {
    int e = blockIdx.x * 256 + threadIdx.x;
    if (e < NE) atomicAdd(&cnt[dst[e]], 1);
}

// ---------- sum of log(cnt+1) ----------
__global__ __launch_bounds__(256) void k_avglog(const int* __restrict__ cnt, float* __restrict__ slot) {
    __shared__ float red[256];
    float s = 0.0f;
    for (int i = blockIdx.x * 256 + threadIdx.x; i < NN; i += gridDim.x * 256)
        s += logf((float)cnt[i] + 1.0f);
    red[threadIdx.x] = s; __syncthreads();
    for (int o = 128; o > 0; o >>= 1) {
        if (threadIdx.x < o) red[threadIdx.x] += red[threadIdx.x + o];
        __syncthreads();
    }
    if (threadIdx.x == 0) atomicAdd(slot, red[0]);
}

// ---------- fused: h0 = x@node_w + node_b  AND amp/att ----------
__global__ __launch_bounds__(256) void k_node(const float* __restrict__ x, const float* __restrict__ w,
                                              const float* __restrict__ b, float* __restrict__ h,
                                              const int* __restrict__ cnt, const float* __restrict__ slot,
                                              float* __restrict__ amp, float* __restrict__ att) {
    int id = blockIdx.x * 256 + threadIdx.x;
    if (id < NN) {
        float avg = slot[0] / (float)NN;
        float c1 = fmaxf((float)cnt[id], 1.0f);
        float lg = logf(c1 + 1.0f);
        amp[id] = lg / avg;
        att[id] = avg / lg;
    }
    if (id >= NN * H) return;
    int n = id / H, j = id - n * H;
    const float* xr = x + (size_t)n * NFD;
    float acc = b[j];
    #pragma unroll
    for (int m = 0; m < NFD; m++) acc += xr[m] * w[m * H + j];
    h[id] = acc;
}

// ---------- exclusive scan of cnt -> offsets (shfl-based) ----------
__global__ __launch_bounds__(1024) void k_scan(const int* __restrict__ cnt, int* __restrict__ offs) {
    __shared__ int wsum[16];
    int tid = threadIdx.x;
    int lane = tid & 63, wv = tid >> 6;
    int runbase = 0;
    for (int base = 0; base < NN; base += 4096) {
        int i0 = base + tid * 4;
        int4 v = make_int4(0, 0, 0, 0);
        if (i0 < NN) v = *(const int4*)(cnt + i0);   // NN % 4 == 0
        int tsum = v.x + v.y + v.z + v.w;
        int x = tsum;
        #pragma unroll
        for (int o = 1; o < 64; o <<= 1) {
            int y = __shfl_up(x, o);
            if (lane >= o) x += y;
        }
        if (lane == 63) wsum[wv] = x;
        __syncthreads();
        if (wv == 0 && lane < 16) {
            int wsv = wsum[lane];
            #pragma unroll
            for (int o = 1; o < 16; o <<= 1) {
                int y = __shfl_up(wsv, o);
                if (lane >= o) wsv += y;
            }
            wsum[lane] = wsv;
        }
        __syncthreads();
        int wpref = (wv > 0) ? wsum[wv - 1] : 0;
        int excl = runbase + wpref + x - tsum;
        if (i0 < NN) {
            offs[i0]     = excl;
            offs[i0 + 1] = excl + v.x;
            offs[i0 + 2] = excl + v.x + v.y;
            offs[i0 + 3] = excl + v.x + v.y + v.z;
        }
        runbase += wsum[15];
        __syncthreads();
    }
    if (tid == 0) offs[NN] = runbase;
}

// ---------- scatter edges into CSR records [ea0..9, src, eid] + pdst ----------
__global__ __launch_bounds__(256) void k_scatter(const int* __restrict__ src, const int* __restrict__ dst,
                                                 const float* __restrict__ edge_attr,
                                                 const int* __restrict__ offs, int* __restrict__ fill,
                                                 float* __restrict__ ea_csr, int* __restrict__ pdst) {
    int e = blockIdx.x * 256 + threadIdx.x;
    if (e >= NE) return;
    int d = dst[e];
    int p = offs[d] + atomicAdd(&fill[d], 1);
    const float2* ear = (const float2*)(edge_attr + (size_t)e * EFD);
    float2 v0 = ear[0], v1 = ear[1], v2 = ear[2], v3 = ear[3], v4 = ear[4];
    float4* o = (float4*)(ea_csr + (size_t)p * REC);
    o[0] = make_float4(v0.x, v0.y, v1.x, v1.y);
    o[1] = make_float4(v2.x, v2.y, v3.x, v3.y);
    o[2] = make_float4(v4.x, v4.y, __int_as_float(src[e]), __int_as_float(e));
    pdst[p] = d;
}

// ---------- per-layer prep: W3e/dvecF + p1T/p2T (+ W1e/b1e on layer 0) ----------
__global__ __launch_bounds__(256) void k_prep1(const float* __restrict__ enc_w, const float* __restrict__ enc_b,
                                               const float* __restrict__ edge_w, const float* __restrict__ edge_b,
                                               const float* __restrict__ pre_w, const float* __restrict__ pre_b,
                                               const float* __restrict__ w1, const float* __restrict__ b1,
                                               float* __restrict__ W3e, float* __restrict__ dvecF,
                                               float* __restrict__ p1T, float* __restrict__ p2T,
                                               float* __restrict__ W1e, float* __restrict__ b1e, int layer) {
    int id = blockIdx.x * 256 + threadIdx.x;
    if (id < EFD * TF) {
        int m = id / TF, j = id - m * TF;
        int t = j / H, f = j - t * H;
        const float* ew = enc_w + (size_t)layer * H * H;
        const float* pw = pre_w + (size_t)(layer * T + t) * 120 * H;
        float acc = 0.0f;
        for (int k = 0; k < H; k++) {
            float wk = edge_w[m * H + k];
            float g = 0.0f;
            #pragma unroll
            for (int o = 0; o < H; o++) g += ew[k * H + o] * pw[(80 + o) * H + f];
            acc += wk * g;
        }
        W3e[m * TF + j] = acc;
        if (m == 0) {
            const float* eb = enc_b + (size_t)layer * H;
            float dacc = pre_b[(size_t)(layer * T + t) * H + f];
            for (int o = 0; o < H; o++) {
                float ebe = eb[o];
                #pragma unroll
                for (int k = 0; k < H; k++) ebe += edge_b[k] * ew[k * H + o];
                dacc += ebe * pw[(80 + o) * H + f];
            }
            dvecF[j] = dacc;
        }
    } else if (id < EFD * TF + TF * H) {
        int id2 = id - EFD * TF;
        int j = id2 / H, m = id2 - j * H;
        int t = j / H, f = j - t * H;
        const float* pw = pre_w + (size_t)(layer * T + t) * 120 * H;
        p1T[id2] = pw[m * H + f];
        p2T[id2] = pw[(H + m) * H + f];
    } else if (layer == 0 && id < EFD * TF + TF * H + EFD * 50) {
        int id2 = id - EFD * TF - TF * H;
        int m = id2 / 50, o = id2 - m * 50;
        float acc = 0.0f;
        #pragma unroll
        for (int k = 0; k < H; k++) acc += edge_w[m * H + k] * w1[(80 + k) * 50 + o];
        W1e[m * 50 + o] = acc;
        if (m == 0) {
            float bacc = b1[o];
            #pragma unroll
            for (int k = 0; k < H; k++) bacc += edge_b[k] * w1[(80 + k) * 50 + o];
            b1e[o] = bacc;
        }
    }
}

// ---------- A = h@P1 (fp32), B = h@P2 (bf16); optional fused BN+residual; 2-node ILP ----------
__global__ __launch_bounds__(256) void k_ab(float* h, const float* __restrict__ cbuf,
                                            const float* __restrict__ bnsum, const float* __restrict__ bnsq,
                                            const float* __restrict__ bng, const float* __restrict__ bnb,
                                            int doBN,
                                            const float* __restrict__ p1T, const float* __restrict__ p2T,
                                            float* __restrict__ A, __hip_bfloat16* __restrict__ Bbf) {
    __shared__ float sh[ABN * H];
    int tid = threadIdx.x;
    int n0 = blockIdx.x * ABN;
    int nodes = NN - n0; if (nodes > ABN) nodes = ABN;
    int nflt4 = nodes * H / 4;               // H%4==0
    const float4* hsrc = (const float4*)(h + (size_t)n0 * H);
    float4* sh4 = (float4*)sh;
    if (doBN) {
        const float4* csrc = (const float4*)(cbuf + (size_t)n0 * H);
        float4* hdst = (float4*)(h + (size_t)n0 * H);
        float invN = 1.0f / (float)NN;
        for (int i4 = tid; i4 < nflt4; i4 += 256) {
            int j4 = (i4 * 4) % H;           // multiple of 4
            float4 hv = hsrc[i4], cv = csrc[i4];
            float4 mu4 = *(const float4*)(bnsum + j4);
            float4 sq4 = *(const float4*)(bnsq + j4);
            float4 g4 = *(const float4*)(bng + j4);
            float4 b4 = *(const float4*)(bnb + j4);
            float4 hn;
            {
                float mu = mu4.x * invN; float var = sq4.x * invN - mu * mu;
                float c = (cv.x - mu) * rsqrtf(var + EPSV) * g4.x + b4.x;
                hn.x = (hv.x + fmaxf(c, 0.0f)) * 0.5f;
            }
            {
                float mu = mu4.y * invN; float var = sq4.y * invN - mu * mu;
                float c = (cv.y - mu) * rsqrtf(var + EPSV) * g4.y + b4.y;
                hn.y = (hv.y + fmaxf(c, 0.0f)) * 0.5f;
            }
            {
                float mu = mu4.z * invN; float var = sq4.z * invN - mu * mu;
                float c = (cv.z - mu) * rsqrtf(var + EPSV) * g4.z + b4.z;
                hn.z = (hv.z + fmaxf(c, 0.0f)) * 0.5f;
            }
            {
                float mu = mu4.w * invN; float var = sq4.w * invN - mu * mu;
                float c = (cv.w - mu) * rsqrtf(var + EPSV) * g4.w + b4.w;
                hn.w = (hv.w + fmaxf(c, 0.0f)) * 0.5f;
            }
            hdst[i4] = hn;                   // materialize h' for k_post
            sh4[i4] = hn;
        }
    } else {
        for (int i4 = tid; i4 < nflt4; i4 += 256) sh4[i4] = hsrc[i4];
    }
    __syncthreads();
    int j = tid;
    if (j >= TF) return;
    float w1r[H], w2r[H];
    const float4* w1p = (const float4*)(p1T + (size_t)j * H);
    const float4* w2p = (const float4*)(p2T + (size_t)j * H);
    #pragma unroll
    for (int m4 = 0; m4 < H / 4; m4++) {
        float4 a = w1p[m4], b = w2p[m4];
        w1r[4 * m4] = a.x; w1r[4 * m4 + 1] = a.y; w1r[4 * m4 + 2] = a.z; w1r[4 * m4 + 3] = a.w;
        w2r[4 * m4] = b.x; w2r[4 * m4 + 1] = b.y; w2r[4 * m4 + 2] = b.z; w2r[4 * m4 + 3] = b.w;
    }
    int n = 0;
    for (; n + 2 <= nodes; n += 2) {         // 2-node ILP: 4 independent FMA chains
        const float4* hr0 = (const float4*)(sh + n * H);
        const float4* hr1 = (const float4*)(sh + (n + 1) * H);
        float a0 = 0.0f, b0 = 0.0f, a1 = 0.0f, b1 = 0.0f;
        #pragma unroll
        for (int m4 = 0; m4 < H / 4; m4++) {
            float4 h0 = hr0[m4], h1 = hr1[m4];      // same addr all lanes -> LDS broadcast
            a0 += h0.x * w1r[4 * m4]     + h0.y * w1r[4 * m4 + 1]
                + h0.z * w1r[4 * m4 + 2] + h0.w * w1r[4 * m4 + 3];
            b0 += h0.x * w2r[4 * m4]     + h0.y * w2r[4 * m4 + 1]
                + h0.z * w2r[4 * m4 + 2] + h0.w * w2r[4 * m4 + 3];
            a1 += h1.x * w1r[4 * m4]     + h1.y * w1r[4 * m4 + 1]
                + h1.z * w1r[4 * m4 + 2] + h1.w * w1r[4 * m4 + 3];
            b1 += h1.x * w2r[4 * m4]     + h1.y * w2r[4 * m4 + 1]
                + h1.z * w2r[4 * m4 + 2] + h1.w * w2r[4 * m4 + 3];
        }
        size_t o0 = (size_t)(n0 + n) * TF + j;      // lanes j consecutive -> coalesced
        A[o0] = a0;
        Bbf[o0] = __float2bfloat16(b0);
        size_t o1 = o0 + TF;
        A[o1] = a1;
        Bbf[o1] = __float2bfloat16(b1);
    }
    if (n < nodes) {
        const float4* hr = (const float4*)(sh + n * H);
        float a = 0.0f, b = 0.0f;
        #pragma unroll
        for (int m4 = 0; m4 < H / 4; m4++) {
            float4 hv = hr[m4];
            a += hv.x * w1r[4 * m4]     + hv.y * w1r[4 * m4 + 1]
               + hv.z * w1r[4 * m4 + 2] + hv.w * w1r[4 * m4 + 3];
            b += hv.x * w2r[4 * m4]     + hv.y * w2r[4 * m4 + 1]
               + hv.z * w2r[4 * m4 + 2] + hv.w * w2r[4 * m4 + 3];
        }
        size_t o = (size_t)(n0 + n) * TF + j;
        A[o] = a;
        Bbf[o] = __float2bfloat16(b);
    }
}

// ---------- aggregation: wave per node, 4-deep pipelined records + bf16 B-gathers ----------
__global__ __launch_bounds__(256) void k_agg(const float* __restrict__ ea_csr,
                                             const __hip_bfloat16* __restrict__ Bbf,
                                             const float* __restrict__ A, const float* __restrict__ w3e,
                                             const float* __restrict__ dvecF, const int* __restrict__ cnt,
                                             const int* __restrict__ offs, float* __restrict__ base) {
    int tid = threadIdx.x;
    int lane = tid & 63;
    int n = __builtin_amdgcn_readfirstlane((int)(blockIdx.x * 4 + (tid >> 6)));   // NN%4==0
    int deg = cnt[n];
    int start = offs[n];
    bool comp = lane < TF / 4; // lanes 0..49
    float4 w3q[EFD];
    float4 dj4 = make_float4(0, 0, 0, 0), a4 = make_float4(0, 0, 0, 0);
    if (comp) {
        #pragma unroll
        for (int m = 0; m < EFD; m++) w3q[m] = *(const float4*)(w3e + m * TF + 4 * lane);
        dj4 = *(const float4*)(dvecF + 4 * lane);
        a4  = *(const float4*)(A + (size_t)n * TF + 4 * lane);
    }
    float sx = 0, sy = 0, sz = 0, sw_ = 0;
    float qx = 0, qy = 0, qz = 0, qw = 0;
    float mnx = 3.4e38f, mny = 3.4e38f, mnz = 3.4e38f, mnw = 3.4e38f;
    float mxx = -3.4e38f, mxy = -3.4e38f, mxz = -3.4e38f, mxw = -3.4e38f;
    const float4* recb = (const float4*)ea_csr + (size_t)start * 3;
    const uint16_t* Bu = (const uint16_t*)Bbf;

    auto edge = [&](float4 qa, float4 qb, float4 qc, uint2 bv) {
        float b0 = __uint_as_float(bv.x << 16);
        float b1 = __uint_as_float(bv.x & 0xffff0000u);
        float b2 = __uint_as_float(bv.y << 16);
        float b3 = __uint_as_float(bv.y & 0xffff0000u);
        float eav[EFD] = {qa.x, qa.y, qa.z, qa.w, qb.x, qb.y, qb.z, qb.w, qc.x, qc.y};
        float cx = dj4.x, cy = dj4.y, cz = dj4.z, cw = dj4.w;
        #pragma unroll
        for (int m = 0; m < EFD; m++) {
            cx = fmaf(eav[m], w3q[m].x, cx);
            cy = fmaf(eav[m], w3q[m].y, cy);
            cz = fmaf(eav[m], w3q[m].z, cz);
            cw = fmaf(eav[m], w3q[m].w, cw);
        }
        float ux = b0 + cx, uy = b1 + cy, uz = b2 + cz, uw = b3 + cw;
        sx += ux; qx = fmaf(ux, ux, qx); mnx = fminf(mnx, ux); mxx = fmaxf(mxx, ux);
        sy += uy; qy = fmaf(uy, uy, qy); mny = fminf(mny, uy); mxy = fmaxf(mxy, uy);
        sz += uz; qz = fmaf(uz, uz, qz); mnz = fminf(mnz, uz); mxz = fmaxf(mxz, uz);
        sw_ += uw; qw = fmaf(uw, uw, qw); mnw = fminf(mnw, uw); mxw = fmaxf(mxw, uw);
    };

    int r = 0;
    for (; r + 4 <= deg; r += 4) {
        float4 qa0 = recb[(r + 0) * 3], qb0 = recb[(r + 0) * 3 + 1], qc0 = recb[(r + 0) * 3 + 2];
        float4 qa1 = recb[(r + 1) * 3], qb1 = recb[(r + 1) * 3 + 1], qc1 = recb[(r + 1) * 3 + 2];
        float4 qa2 = recb[(r + 2) * 3], qb2 = recb[(r + 2) * 3 + 1], qc2 = recb[(r + 2) * 3 + 2];
        float4 qa3 = recb[(r + 3) * 3], qb3 = recb[(r + 3) * 3 + 1], qc3 = recb[(r + 3) * 3 + 2];
        int s0 = __float_as_int(qc0.z), s1 = __float_as_int(qc1.z);
        int s2 = __float_as_int(qc2.z), s3 = __float_as_int(qc3.z);
        if (comp) {
            uint2 v0 = *(const uint2*)(Bu + (size_t)s0 * TF + 4 * lane);
            uint2 v1 = *(const uint2*)(Bu + (size_t)s1 * TF + 4 * lane);
            uint2 v2 = *(const uint2*)(Bu + (size_t)s2 * TF + 4 * lane);
            uint2 v3 = *(const uint2*)(Bu + (size_t)s3 * TF + 4 * lane);
            edge(qa0, qb0, qc0, v0);
            edge(qa1, qb1, qc1, v1);
            edge(qa2, qb2, qc2, v2);
            edge(qa3, qb3, qc3, v3);
        }
    }
    for (; r < deg; r++) {
        float4 qa = recb[r * 3], qb = recb[r * 3 + 1], qc = recb[r * 3 + 2];
        int sn = __float_as_int(qc.z);
        if (comp) {
            uint2 bv = *(const uint2*)(Bu + (size_t)sn * TF + 4 * lane);
            edge(qa, qb, qc, bv);
        }
    }
    if (comp) {
        float d = (float)deg, c1 = fmaxf(d, 1.0f);
        float inv = 1.0f / c1;
        float mex = (d * a4.x + sx) * inv, mey = (d * a4.y + sy) * inv;
        float mez = (d * a4.z + sz) * inv, mew = (d * a4.w + sw_) * inv;
        float msx = (d * a4.x * a4.x + 2.0f * a4.x * sx + qx) * inv;
        float msy = (d * a4.y * a4.y + 2.0f * a4.y * sy + qy) * inv;
        float msz = (d * a4.z * a4.z + 2.0f * a4.z * sz + qz) * inv;
        float msw = (d * a4.w * a4.w + 2.0f * a4.w * sw_ + qw) * inv;
        float4 mean4 = make_float4(mex, mey, mez, mew);
        float4 sd4 = make_float4(sqrtf(fmaxf(msx - mex * mex, 0.0f) + EPSV),
                                 sqrtf(fmaxf(msy - mey * mey, 0.0f) + EPSV),
                                 sqrtf(fmaxf(msz - mez * mez, 0.0f) + EPSV),
                                 sqrtf(fmaxf(msw - mew * mew, 0.0f) + EPSV));
        bool has = deg > 0;
        float4 mnv4 = has ? make_float4(a4.x + mnx, a4.y + mny, a4.z + mnz, a4.w + mnw)
                          : make_float4(0, 0, 0, 0);
        float4 mxv4 = has ? make_float4(a4.x + mxx, a4.y + mxy, a4.z + mxz, a4.w + mxw)
                          : make_float4(0, 0, 0, 0);
        int j0 = 4 * lane;
        int t = j0 / H, f = j0 - t * H;
        float* bb = base + (size_t)n * BASE_W + t * 160 + f;
        *(float4*)(bb)       = mean4;
        *(float4*)(bb + 40)  = mnv4;
        *(float4*)(bb + 80)  = mxv4;
        *(float4*)(bb + 120) = sd4;
    }
}

// ---------- post einsum, t-split: 2 nodes/thread share LDS weight reads ----------
__global__ __launch_bounds__(256) void k_post(const float* __restrict__ h, const float* __restrict__ base,
                                              const float* __restrict__ amp, const float* __restrict__ att,
                                              const float* __restrict__ post_w, const float* __restrict__ post_b,
                                              float* __restrict__ cpre, int layer) {
    __shared__ float ws[FO * WS_PAD];
    int tid = threadIdx.x;
    int t = blockIdx.y;
    const float* pwsrc = post_w + (size_t)(layer * T + t) * 520 * FO;
    for (int i = tid; i < 520 * FO; i += 256) {
        int g = i >> 3, o = i & 7;
        ws[o * WS_PAD + g] = pwsrc[i];
    }
    __syncthreads();
    int slot = tid >> 3, o = tid & 7;          // slot 0..31 -> node pair
    int n0 = blockIdx.x * 64 + slot * 2;
    if (n0 >= NN) return;
    int n1 = n0 + 1;
    bool two = (n1 < NN);
    if (!two) n1 = n0;
    const float* wrow = ws + o * WS_PAD;
    float am0 = amp[n0], at0 = att[n0];
    float am1 = amp[n1], at1 = att[n1];
    float pb = post_b[(size_t)(layer * T + t) * FO + o];
    float acc0 = pb, acc1 = pb;
    const float4* hx0 = (const float4*)(h + (size_t)n0 * H);
    const float4* hx1 = (const float4*)(h + (size_t)n1 * H);
    #pragma unroll
    for (int g4 = 0; g4 < 10; g4++) {
        float4 wv = *(const float4*)(wrow + g4 * 4);
        float4 x0 = hx0[g4], x1 = hx1[g4];
        acc0 += x0.x * wv.x + x0.y * wv.y + x0.z * wv.z + x0.w * wv.w;
        acc1 += x1.x * wv.x + x1.y * wv.y + x1.z * wv.z + x1.w * wv.w;
    }
    const float4* b0 = (const float4*)(base + (size_t)n0 * BASE_W + t * 160);
    const float4* b1 = (const float4*)(base + (size_t)n1 * BASE_W + t * 160);
    #pragma unroll 8
    for (int g4 = 0; g4 < 40; g4++) {
        float4 wa = *(const float4*)(wrow + 40 + g4 * 4);
        float4 wb = *(const float4*)(wrow + 200 + g4 * 4);
        float4 wc = *(const float4*)(wrow + 360 + g4 * 4);
        float4 v0 = b0[g4], v1 = b1[g4];
        acc0 += v0.x * (wa.x + am0 * wb.x + at0 * wc.x)
              + v0.y * (wa.y + am0 * wb.y + at0 * wc.y)
              + v0.z * (wa.z + am0 * wb.z + at0 * wc.z)
              + v0.w * (wa.w + am0 * wb.w + at0 * wc.w);
        acc1 += v1.x * (wa.x + am1 * wb.x + at1 * wc.x)
              + v1.y * (wa.y + am1 * wb.y + at1 * wc.y)
              + v1.z * (wa.z + am1 * wb.z + at1 * wc.z)
              + v1.w * (wa.w + am1 * wb.w + at1 * wc.w);
    }
    cpre[(size_t)n0 * H + t * FO + o] = acc0;
    if (two) cpre[(size_t)n1 * H + t * FO + o] = acc1;
}

// ---------- fused lin + BN-stats ----------
__global__ __launch_bounds__(256) void k_linbn(const float* __restrict__ cpre, const float* __restrict__ lin_w,
                                               const float* __restrict__ lin_b, float* __restrict__ cbuf,
                                               float* __restrict__ bnsum, float* __restrict__ bnsq, int layer) {
    __shared__ float scp[240];
    __shared__ float red[80];
    int tid = threadIdx.x;
    int j = tid % H, nl = tid / H;
    const float* lw = lin_w + (size_t)layer * H * H;
    float wcol[H];
    #pragma unroll
    for (int k = 0; k < H; k++) wcol[k] = lw[k * H + j];
    float lb = lin_b[(size_t)layer * H + j];
    float lsum = 0.0f, lsq = 0.0f;
    for (int n0 = blockIdx.x * 6; n0 < NN; n0 += gridDim.x * 6) {
        int nn = NN - n0; if (nn > 6) nn = 6;
        if (tid < nn * H) scp[tid] = cpre[(size_t)n0 * H + tid];
        __syncthreads();
        if (nl < nn) {
            float acc = lb;
            #pragma unroll
            for (int k = 0; k < H; k++) acc += scp[nl * H + k] * wcol[k];
            cbuf[(size_t)(n0 + nl) * H + j] = acc;
            lsum += acc; lsq += acc * acc;
        }
        __syncthreads();
    }
    if (tid < 80) red[tid] = 0.0f;
    __syncthreads();
    if (nl < 6) { atomicAdd(&red[j], lsum); atomicAdd(&red[40 + j], lsq); }
    __syncthreads();
    if (tid < 40) atomicAdd(&bnsum[tid], red[tid]);
    else if (tid < 80) atomicAdd(&bnsq[tid - 40], red[tid]);
}

// ---------- final prep: fused BN(layer1)+residual in LDS, then P1/P2 (5 nodes/block) ----------
__global__ __launch_bounds__(256) void k_prep2(const float* __restrict__ h, const float* __restrict__ cbuf,
                                               const float* __restrict__ bnsum, const float* __restrict__ bnsq,
                                               const float* __restrict__ bng, const float* __restrict__ bnb,
                                               const float* __restrict__ w1,
                                               float* __restrict__ P1, float* __restrict__ P2) {
    __shared__ float sh[5 * H];
    int tid = threadIdx.x;
    int n0 = blockIdx.x * 5;                 // NN % 5 == 0
    if (tid < 5 * H) {
        int j = tid % H;
        float invN = 1.0f / (float)NN;
        float mu = bnsum[j] * invN;
        float var = bnsq[j] * invN - mu * mu;
        float inv = rsqrtf(var + EPSV);
        float cv = (cbuf[(size_t)n0 * H + tid] - mu) * inv * bng[j] + bnb[j];
        sh[tid] = (h[(size_t)n0 * H + tid] + fmaxf(cv, 0.0f)) * 0.5f;
    }
    __syncthreads();
    if (tid >= 250) return;
    int nl = tid / 50, o = tid - nl * 50;
    const float* hr = sh + nl * H;
    float a1 = 0.0f, a2 = 0.0f;
    #pragma unroll
    for (int f = 0; f < H; f++) {
        float v = fmaxf(hr[f], 0.0f);
        a1 += v * w1[f * 50 + o];
        a2 += v * w1[(H + f) * 50 + o];
    }
    P1[(size_t)(n0 + nl) * PSTR + o] = a1;
    P2[(size_t)(n0 + nl) * PSTR + o] = a2;
}

// ---------- final edge MLP: all weights via uniform scalar loads (no LDS) ----------
__global__ __launch_bounds__(256) void k_mlp(const float* __restrict__ ea_csr, const int* __restrict__ pdst,
                                             const float* __restrict__ P1, const float* __restrict__ P2,
                                             const float* __restrict__ W1e, const float* __restrict__ b1e,
                                             const float* __restrict__ w2, const float* __restrict__ b2,
                                             const float* __restrict__ w3, const float* __restrict__ b3,
                                             float* __restrict__ out) {
    int p = blockIdx.x * 256 + threadIdx.x;
    if (p >= NE) return;
    const float4* rec = (const float4*)ea_csr + (size_t)p * 3;
    float4 r0 = rec[0], r1 = rec[1], r2 = rec[2];
    int s = __float_as_int(r2.z), eid = __float_as_int(r2.w);
    int d = pdst[p];
    float ea[EFD] = {r0.x, r0.y, r0.z, r0.w, r1.x, r1.y, r1.z, r1.w, r2.x, r2.y};

    float z1[52];
    const float4* p1r = (const float4*)(P1 + (size_t)s * PSTR);
    const float4* p2r = (const float4*)(P2 + (size_t)d * PSTR);
    #pragma unroll
    for (int i = 0; i < 13; i++) {
        float4 a = p1r[i], b = p2r[i];
        z1[4 * i]     = a.x + b.x;
        z1[4 * i + 1] = a.y + b.y;
        z1[4 * i + 2] = a.z + b.z;
        z1[4 * i + 3] = a.w + b.w;
    }
    #pragma unroll
    for (int k = 0; k < 50; k++) z1[k] += b1e[k];              // uniform -> scalar
    #pragma unroll
    for (int m = 0; m < EFD; m++) {
        float v = ea[m];
        #pragma unroll
        for (int k = 0; k < 50; k++) z1[k] = fmaf(v, W1e[m * 50 + k], z1[k]);
    }
    float z2[25];
    #pragma unroll
    for (int o = 0; o < 25; o++) z2[o] = b2[o];
    #pragma unroll
    for (int k = 0; k < 50; k++) {
        float v = fmaxf(z1[k], 0.0f);
        #pragma unroll
        for (int o = 0; o < 25; o++) z2[o] = fmaf(v, w2[k * 25 + o], z2[o]);
    }
    float o0 = b3[0], o1 = b3[1];
    #pragma unroll
    for (int k = 0; k < 25; k++) {
        float v = fmaxf(z2[k], 0.0f);
        o0 = fmaf(v, w3[k * 2], o0);
        o1 = fmaf(v, w3[k * 2 + 1], o1);
    }
    *(float2*)(out + (size_t)eid * 2) = make_float2(o0, o1);
}

extern "C" void kernel_launch(void* const* d_in, const int* in_sizes, int n_in,
                              void* d_out, int out_size, void* d_ws, size_t ws_size,
                              hipStream_t stream) {
    const float* x         = (const float*)d_in[0];
    const float* edge_attr = (const float*)d_in[1];
    const int*   eidx      = (const int*)  d_in[2];
    const float* node_w    = (const float*)d_in[3];
    const float* node_b    = (const float*)d_in[4];
    const float* edge_w    = (const float*)d_in[5];
    const float* edge_b    = (const float*)d_in[6];
    const float* enc_w     = (const float*)d_in[7];
    const float* enc_b     = (const float*)d_in[8];
    const float* pre_w     = (const float*)d_in[9];
    const float* pre_b     = (const float*)d_in[10];
    const float* post_w    = (const float*)d_in[11];
    const float* post_b    = (const float*)d_in[12];
    const float* lin_w     = (const float*)d_in[13];
    const float* lin_b     = (const float*)d_in[14];
    const float* bn_g      = (const float*)d_in[15];
    const float* bn_b      = (const float*)d_in[16];
    const float* w1 = (const float*)d_in[17];
    const float* b1 = (const float*)d_in[18];
    const float* w2 = (const float*)d_in[19];
    const float* b2 = (const float*)d_in[20];
    const float* w3 = (const float*)d_in[21];
    const float* b3 = (const float*)d_in[22];
    const int* srcp = eidx;
    const int* dstp = eidx + NE;
    float* out = (float*)d_out;

    char* ws = (char*)d_ws;
    size_t off = 0;
    auto alloc = [&](size_t bytes) -> char* {
        char* p = ws + off;
        off += (bytes + 255) & ~(size_t)255;
        return p;
    };
    float* h      = (float*)alloc((size_t)NN * H * 4);
    float* Abuf   = (float*)alloc((size_t)NN * TF * 4);
    float* cbuf   = (float*)alloc((size_t)NN * H * 4);
    __hip_bfloat16* Bbf = (__hip_bfloat16*)alloc((size_t)NN * TF * 2 + 256);
    float* base   = (float*)alloc((size_t)NN * BASE_W * 4);
    float* cpre   = (float*)alloc((size_t)NN * H * 4);
    float* ea_csr = (float*)alloc((size_t)NE * REC * 4);
    int* pdst     = (int*)alloc((size_t)NE * 4);
    float* W3e    = (float*)alloc((size_t)EFD * TF * 4);
    float* dvecF  = (float*)alloc((size_t)TF * 4);
    float* p1T    = (float*)alloc((size_t)TF * H * 4);
    float* p2T    = (float*)alloc((size_t)TF * H * 4);
    float* P1     = (float*)alloc((size_t)NN * PSTR * 4);
    float* P2     = (float*)alloc((size_t)NN * PSTR * 4);
    float* W1e    = (float*)alloc((size_t)EFD * 50 * 4);
    float* b1e    = (float*)alloc((size_t)64 * 4);
    float* amp    = (float*)alloc((size_t)NN * 4);
    float* att    = (float*)alloc((size_t)NN * 4);
    int* offs     = (int*)alloc((size_t)(NN + 1) * 4);
    // ---- contiguous zero region: cnt, fill, avgs, bnz(2 layers) ----
    size_t zoff = off;
    int* cnt_i    = (int*)alloc((size_t)NN * 4);
    int* fill     = (int*)alloc((size_t)NN * 4);
    float* avgs   = (float*)alloc(256);
    float* bnz    = (float*)alloc(1024);   // layer l: bnz + l*128 floats (sum 40 | sq 40)
    size_t zsize = off - zoff;
    if (off > ws_size) return;

    hipMemsetAsync(cnt_i, 0, zsize, stream);

    k_deg<<<(NE + 255) / 256, 256, 0, stream>>>(dstp, cnt_i);
    k_avglog<<<64, 256, 0, stream>>>(cnt_i, avgs);
    k_node<<<(NN * H + 255) / 256, 256, 0, stream>>>(x, node_w, node_b, h, cnt_i, avgs, amp, att);
    k_scan<<<1, 1024, 0, stream>>>(cnt_i, offs);
    k_scatter<<<(NE + 255) / 256, 256, 0, stream>>>(srcp, dstp, edge_attr, offs, fill, ea_csr, pdst);

    int prep1_grid = (EFD * TF + TF * H + EFD * 50 + 255) / 256;
    for (int layer = 0; layer < LAYERS; layer++) {
        float* bnzL = bnz + layer * 128;
        k_prep1<<<prep1_grid, 256, 0, stream>>>(
            enc_w, enc_b, edge_w, edge_b, pre_w, pre_b, w1, b1,
            W3e, dvecF, p1T, p2T, W1e, b1e, layer);
        float* bnzP = bnz + (layer - 1) * 128;
        k_ab<<<(NN + ABN - 1) / ABN, 256, 0, stream>>>(
            h, cbuf, (layer > 0) ? bnzP : bnz, (layer > 0) ? bnzP + 40 : bnz,
            bn_g + (size_t)(layer > 0 ? layer - 1 : 0) * H,
            bn_b + (size_t)(layer > 0 ? layer - 1 : 0) * H,
            (layer > 0) ? 1 : 0, p1T, p2T, Abuf, Bbf);
        k_agg<<<NN / 4, 256, 0, stream>>>(ea_csr, Bbf, Abuf, W3e, dvecF, cnt_i, offs, base);
        k_post<<<dim3((NN + 63) / 64, T), 256, 0, stream>>>(h, base, amp, att, post_w, post_b, cpre, layer);
        k_linbn<<<1024, 256, 0, stream>>>(cpre, lin_w, lin_b, cbuf, bnzL, bnzL + 40, layer);
    }
    k_prep2<<<NN / 5, 256, 0, stream>>>(h, cbuf, bnz + 128, bnz + 168,
                                        bn_g + H, bn_b + H, w1, P1, P2);
    k_mlp<<<(NE + 255) / 256, 256, 0, stream>>>(ea_csr, pdst, P1, P2, W1e, b1e, w2, b2, w3, b3, out);
}

// Round 11
// 594.995 us; speedup vs baseline: 1.0934x; 1.0934x over previous
//
#include <hip/hip_runtime.h>
#include <hip/hip_bf16.h>
#include <cstdint>
#include <cstddef>

#define NN 25000
#define NE 400000
#define NFD 30
#define EFD 10
#define H 40
#define T 5
#define FO 8
#define LAYERS 2
#define TF 200          // T*F
#define BASE_W 800      // T*160
#define PSTR 52         // padded row stride for P1/P2
#define WS_PAD 532      // padded LDS row stride (floats) for post weights
#define REC 12          // floats per CSR edge record [ea0..9, src, eid]
#define WCN 416         // Wcat rows: A j 0..199 | pad | B j 208..407 | pad
#define WCK 64          // Wcat K (40 real + 24 zero-pad)
#define SHP 72          // LDS bf16 row stride for h tile
#define EPSV 1e-5f

typedef __attribute__((ext_vector_type(8))) short bf16x8;
typedef __attribute__((ext_vector_type(4))) float f32x4;

__device__ inline short bfbits(float v) {
    __hip_bfloat16 b = __float2bfloat16(v);
    return *(short*)&b;
}

// ---------- degree histogram ----------
__global__ __launch_bounds__(256) void k_deg(const int* __restrict__ dst, int* __restrict__ cnt) {
    int e = blockIdx.x * 256 + threadIdx.x;
    if (e < NE) atomicAdd(&cnt[dst[e]], 1);
}

// ---------- sum of log(cnt+1) ----------
__global__ __launch_bounds__(256) void k_avglog(const int* __restrict__ cnt, float* __restrict__ slot) {
    __shared__ float red[256];
    float s = 0.0f;
    for (int i = blockIdx.x * 256 + threadIdx.x; i < NN; i += gridDim.x * 256)
        s += logf((float)cnt[i] + 1.0f);
    red[threadIdx.x] = s; __syncthreads();
    for (int o = 128; o > 0; o >>= 1) {
        if (threadIdx.x < o) red[threadIdx.x] += red[threadIdx.x + o];
        __syncthreads();
    }
    if (threadIdx.x == 0) atomicAdd(slot, red[0]);
}

// ---------- fused: h0 = x@node_w + node_b  AND amp/att ----------
__global__ __launch_bounds__(256) void k_node(const float* __restrict__ x, const float* __restrict__ w,
                                              const float* __restrict__ b, float* __restrict__ h,
                                              const int* __restrict__ cnt, const float* __restrict__ slot,
                                              float* __restrict__ amp, float* __restrict__ att) {
    int id = blockIdx.x * 256 + threadIdx.x;
    if (id < NN) {
        float avg = slot[0] / (float)NN;
        float c1 = fmaxf((float)cnt[id], 1.0f);
        float lg = logf(c1 + 1.0f);
        amp[id] = lg / avg;
        att[id] = avg / lg;
    }
    if (id >= NN * H) return;
    int n = id / H, j = id - n * H;
    const float* xr = x + (size_t)n * NFD;
    float acc = b[j];
    #pragma unroll
    for (int m = 0; m < NFD; m++) acc += xr[m] * w[m * H + j];
    h[id] = acc;
}

// ---------- exclusive scan of cnt -> offsets (shfl-based) ----------
__global__ __launch_bounds__(1024) void k_scan(const int* __restrict__ cnt, int* __restrict__ offs) {
    __shared__ int wsum[16];
    int tid = threadIdx.x;
    int lane = tid & 63, wv = tid >> 6;
    int runbase = 0;
    for (int base = 0; base < NN; base += 4096) {
        int i0 = base + tid * 4;
        int4 v = make_int4(0, 0, 0, 0);
        if (i0 < NN) v = *(const int4*)(cnt + i0);   // NN % 4 == 0
        int tsum = v.x + v.y + v.z + v.w;
        int x = tsum;
        #pragma unroll
        for (int o = 1; o < 64; o <<= 1) {
            int y = __shfl_up(x, o);
            if (lane >= o) x += y;
        }
        if (lane == 63) wsum[wv] = x;
        __syncthreads();
        if (wv == 0 && lane < 16) {
            int wsv = wsum[lane];
            #pragma unroll
            for (int o = 1; o < 16; o <<= 1) {
                int y = __shfl_up(wsv, o);
                if (lane >= o) wsv += y;
            }
            wsum[lane] = wsv;
        }
        __syncthreads();
        int wpref = (wv > 0) ? wsum[wv - 1] : 0;
        int excl = runbase + wpref + x - tsum;
        if (i0 < NN) {
            offs[i0]     = excl;
            offs[i0 + 1] = excl + v.x;
            offs[i0 + 2] = excl + v.x + v.y;
            offs[i0 + 3] = excl + v.x + v.y + v.z;
        }
        runbase += wsum[15];
        __syncthreads();
    }
    if (tid == 0) offs[NN] = runbase;
}

// ---------- scatter edges into CSR records [ea0..9, src, eid] + pdst ----------
__global__ __launch_bounds__(256) void k_scatter(const int* __restrict__ src, const int* __restrict__ dst,
                                                 const float* __restrict__ edge_attr,
                                                 const int* __restrict__ offs, int* __restrict__ fill,
                                                 float* __restrict__ ea_csr, int* __restrict__ pdst) {
    int e = blockIdx.x * 256 + threadIdx.x;
    if (e >= NE) return;
    int d = dst[e];
    int p = offs[d] + atomicAdd(&fill[d], 1);
    const float2* ear = (const float2*)(edge_attr + (size_t)e * EFD);
    float2 v0 = ear[0], v1 = ear[1], v2 = ear[2], v3 = ear[3], v4 = ear[4];
    float4* o = (float4*)(ea_csr + (size_t)p * REC);
    o[0] = make_float4(v0.x, v0.y, v1.x, v1.y);
    o[1] = make_float4(v2.x, v2.y, v3.x, v3.y);
    o[2] = make_float4(v4.x, v4.y, __int_as_float(src[e]), __int_as_float(e));
    pdst[p] = d;
}

// ---------- per-layer prep: W3e/dvecF + Wcat (bf16 MFMA weights) + W1e/b1e (layer 0) ----------
__global__ __launch_bounds__(256) void k_prep1(const float* __restrict__ enc_w, const float* __restrict__ enc_b,
                                               const float* __restrict__ edge_w, const float* __restrict__ edge_b,
                                               const float* __restrict__ pre_w, const float* __restrict__ pre_b,
                                               const float* __restrict__ w1, const float* __restrict__ b1,
                                               float* __restrict__ W3e, float* __restrict__ dvecF,
                                               __hip_bfloat16* __restrict__ Wcat,
                                               float* __restrict__ W1e, float* __restrict__ b1e, int layer) {
    int id = blockIdx.x * 256 + threadIdx.x;
    if (id < EFD * TF) {
        int m = id / TF, j = id - m * TF;
        int t = j / H, f = j - t * H;
        const float* ew = enc_w + (size_t)layer * H * H;
        const float* pw = pre_w + (size_t)(layer * T + t) * 120 * H;
        float acc = 0.0f;
        for (int k = 0; k < H; k++) {
            float wk = edge_w[m * H + k];
            float g = 0.0f;
            #pragma unroll
            for (int o = 0; o < H; o++) g += ew[k * H + o] * pw[(80 + o) * H + f];
            acc += wk * g;
        }
        W3e[m * TF + j] = acc;
        if (m == 0) {
            const float* eb = enc_b + (size_t)layer * H;
            float dacc = pre_b[(size_t)(layer * T + t) * H + f];
            for (int o = 0; o < H; o++) {
                float ebe = eb[o];
                #pragma unroll
                for (int k = 0; k < H; k++) ebe += edge_b[k] * ew[k * H + o];
                dacc += ebe * pw[(80 + o) * H + f];
            }
            dvecF[j] = dacc;
        }
    } else if (id < EFD * TF + WCN * WCK) {
        int id2 = id - EFD * TF;
        int j = id2 / WCK, k = id2 - j * WCK;
        float val = 0.0f;
        if (k < H) {
            if (j < TF) {                      // A weights: p1 part, pre_w[t][k][f]
                int t = j / H, f = j - t * H;
                val = pre_w[((size_t)(layer * T + t) * 120 + k) * H + f];
            } else if (j >= 208 && j < 208 + TF) {   // B weights: p2 part, pre_w[t][40+k][f]
                int j2 = j - 208;
                int t = j2 / H, f = j2 - t * H;
                val = pre_w[((size_t)(layer * T + t) * 120 + H + k) * H + f];
            }
        }
        Wcat[id2] = __float2bfloat16(val);
    } else if (layer == 0 && id < EFD * TF + WCN * WCK + EFD * 50) {
        int id2 = id - EFD * TF - WCN * WCK;
        int m = id2 / 50, o = id2 - m * 50;
        float acc = 0.0f;
        #pragma unroll
        for (int k = 0; k < H; k++) acc += edge_w[m * H + k] * w1[(80 + k) * 50 + o];
        W1e[m * 50 + o] = acc;
        if (m == 0) {
            float bacc = b1[o];
            #pragma unroll
            for (int k = 0; k < H; k++) bacc += edge_b[k] * w1[(80 + k) * 50 + o];
            b1e[o] = bacc;
        }
    }
}

// ---------- MFMA A/B: [64 nodes x 40] @ Wcat -> A fp32, Bbf bf16; fused BN+residual ----------
__global__ __launch_bounds__(256) void k_abm(float* h, const float* __restrict__ cbuf,
                                             const float* __restrict__ bnsum, const float* __restrict__ bnsq,
                                             const float* __restrict__ bng, const float* __restrict__ bnb,
                                             int doBN,
                                             const __hip_bfloat16* __restrict__ Wcat,
                                             float* __restrict__ A, __hip_bfloat16* __restrict__ Bbf) {
    __shared__ short sh[64 * SHP];           // bf16 bits, zero-padded K
    int tid = threadIdx.x;
    int n0 = blockIdx.x * 64;
    int nodes = NN - n0; if (nodes > 64) nodes = 64;
    for (int i = tid; i < 64 * SHP; i += 256) sh[i] = 0;
    __syncthreads();
    float invN = 1.0f / (float)NN;
    for (int i = tid; i < nodes * H; i += 256) {
        int f = i % H;
        float hv = h[(size_t)n0 * H + i];
        float hn;
        if (doBN) {
            float mu = bnsum[f] * invN;
            float var = bnsq[f] * invN - mu * mu;
            float c = (cbuf[(size_t)n0 * H + i] - mu) * rsqrtf(var + EPSV) * bng[f] + bnb[f];
            hn = (hv + fmaxf(c, 0.0f)) * 0.5f;
            h[(size_t)n0 * H + i] = hn;      // materialize h' for k_post
        } else {
            hn = hv;
        }
        sh[(i / H) * SHP + f] = bfbits(hn);
    }
    __syncthreads();

    int wv = tid >> 6, lane = tid & 63;
    int q = lane >> 4, c16 = lane & 15;
    const short* arow = sh + (wv * 16 + c16) * SHP + q * 8;
    bf16x8 a0 = *(const bf16x8*)(arow);       // k = q*8..q*8+7   (chunk 0: K 0..31)
    bf16x8 a1 = *(const bf16x8*)(arow + 32);  // chunk 1: K 32..63 (zeros beyond 40)
    int gm = n0 + wv * 16 + q * 4;            // D rows: gm..gm+3 (row = quad*4+reg)

    for (int jt = 0; jt < 26; jt++) {
        int col = jt * 16 + c16;
        const short* wrow = (const short*)Wcat + (size_t)col * WCK + q * 8;
        bf16x8 b0 = *(const bf16x8*)(wrow);
        bf16x8 b1 = *(const bf16x8*)(wrow + 32);
        f32x4 acc = {0.0f, 0.0f, 0.0f, 0.0f};
        acc = __builtin_amdgcn_mfma_f32_16x16x32_bf16(a0, b0, acc, 0, 0, 0);
        acc = __builtin_amdgcn_mfma_f32_16x16x32_bf16(a1, b1, acc, 0, 0, 0);
        if (col < TF) {                       // A region
            #pragma unroll
            for (int r = 0; r < 4; r++) {
                int row = gm + r;
                if (row < NN) A[(size_t)row * TF + col] = acc[r];
            }
        } else if (col >= 208) {
            int c2 = col - 208;
            if (c2 < TF) {                    // B region
                #pragma unroll
                for (int r = 0; r < 4; r++) {
                    int row = gm + r;
                    if (row < NN) Bbf[(size_t)row * TF + c2] = __float2bfloat16(acc[r]);
                }
            }
        }
    }
}

// ---------- aggregation: wave per node, 4-deep pipelined records + bf16 B-gathers ----------
__global__ __launch_bounds__(256) void k_agg(const float* __restrict__ ea_csr,
                                             const __hip_bfloat16* __restrict__ Bbf,
                                             const float* __restrict__ A, const float* __restrict__ w3e,
                                             const float* __restrict__ dvecF, const int* __restrict__ cnt,
                                             const int* __restrict__ offs, float* __restrict__ base) {
    int tid = threadIdx.x;
    int lane = tid & 63;
    int n = __builtin_amdgcn_readfirstlane((int)(blockIdx.x * 4 + (tid >> 6)));   // NN%4==0
    int deg = cnt[n];
    int start = offs[n];
    bool comp = lane < TF / 4; // lanes 0..49
    float4 w3q[EFD];
    float4 dj4 = make_float4(0, 0, 0, 0), a4 = make_float4(0, 0, 0, 0);
    if (comp) {
        #pragma unroll
        for (int m = 0; m < EFD; m++) w3q[m] = *(const float4*)(w3e + m * TF + 4 * lane);
        dj4 = *(const float4*)(dvecF + 4 * lane);
        a4  = *(const float4*)(A + (size_t)n * TF + 4 * lane);
    }
    float sx = 0, sy = 0, sz = 0, sw_ = 0;
    float qx = 0, qy = 0, qz = 0, qw = 0;
    float mnx = 3.4e38f, mny = 3.4e38f, mnz = 3.4e38f, mnw = 3.4e38f;
    float mxx = -3.4e38f, mxy = -3.4e38f, mxz = -3.4e38f, mxw = -3.4e38f;
    const float4* recb = (const float4*)ea_csr + (size_t)start * 3;
    const uint16_t* Bu = (const uint16_t*)Bbf;

    auto edge = [&](float4 qa, float4 qb, float4 qc, uint2 bv) {
        float b0 = __uint_as_float(bv.x << 16);
        float b1 = __uint_as_float(bv.x & 0xffff0000u);
        float b2 = __uint_as_float(bv.y << 16);
        float b3 = __uint_as_float(bv.y & 0xffff0000u);
        float eav[EFD] = {qa.x, qa.y, qa.z, qa.w, qb.x, qb.y, qb.z, qb.w, qc.x, qc.y};
        float cx = dj4.x, cy = dj4.y, cz = dj4.z, cw = dj4.w;
        #pragma unroll
        for (int m = 0; m < EFD; m++) {
            cx = fmaf(eav[m], w3q[m].x, cx);
            cy = fmaf(eav[m], w3q[m].y, cy);
            cz = fmaf(eav[m], w3q[m].z, cz);
            cw = fmaf(eav[m], w3q[m].w, cw);
        }
        float ux = b0 + cx, uy = b1 + cy, uz = b2 + cz, uw = b3 + cw;
        sx += ux; qx = fmaf(ux, ux, qx); mnx = fminf(mnx, ux); mxx = fmaxf(mxx, ux);
        sy += uy; qy = fmaf(uy, uy, qy); mny = fminf(mny, uy); mxy = fmaxf(mxy, uy);
        sz += uz; qz = fmaf(uz, uz, qz); mnz = fminf(mnz, uz); mxz = fmaxf(mxz, uz);
        sw_ += uw; qw = fmaf(uw, uw, qw); mnw = fminf(mnw, uw); mxw = fmaxf(mxw, uw);
    };

    int r = 0;
    for (; r + 4 <= deg; r += 4) {
        float4 qa0 = recb[(r + 0) * 3], qb0 = recb[(r + 0) * 3 + 1], qc0 = recb[(r + 0) * 3 + 2];
        float4 qa1 = recb[(r + 1) * 3], qb1 = recb[(r + 1) * 3 + 1], qc1 = recb[(r + 1) * 3 + 2];
        float4 qa2 = recb[(r + 2) * 3], qb2 = recb[(r + 2) * 3 + 1], qc2 = recb[(r + 2) * 3 + 2];
        float4 qa3 = recb[(r + 3) * 3], qb3 = recb[(r + 3) * 3 + 1], qc3 = recb[(r + 3) * 3 + 2];
        int s0 = __float_as_int(qc0.z), s1 = __float_as_int(qc1.z);
        int s2 = __float_as_int(qc2.z), s3 = __float_as_int(qc3.z);
        if (comp) {
            uint2 v0 = *(const uint2*)(Bu + (size_t)s0 * TF + 4 * lane);
            uint2 v1 = *(const uint2*)(Bu + (size_t)s1 * TF + 4 * lane);
            uint2 v2 = *(const uint2*)(Bu + (size_t)s2 * TF + 4 * lane);
            uint2 v3 = *(const uint2*)(Bu + (size_t)s3 * TF + 4 * lane);
            edge(qa0, qb0, qc0, v0);
            edge(qa1, qb1, qc1, v1);
            edge(qa2, qb2, qc2, v2);
            edge(qa3, qb3, qc3, v3);
        }
    }
    for (; r < deg; r++) {
        float4 qa = recb[r * 3], qb = recb[r * 3 + 1], qc = recb[r * 3 + 2];
        int sn = __float_as_int(qc.z);
        if (comp) {
            uint2 bv = *(const uint2*)(Bu + (size_t)sn * TF + 4 * lane);
            edge(qa, qb, qc, bv);
        }
    }
    if (comp) {
        float d = (float)deg, c1 = fmaxf(d, 1.0f);
        float inv = 1.0f / c1;
        float mex = (d * a4.x + sx) * inv, mey = (d * a4.y + sy) * inv;
        float mez = (d * a4.z + sz) * inv, mew = (d * a4.w + sw_) * inv;
        float msx = (d * a4.x * a4.x + 2.0f * a4.x * sx + qx) * inv;
        float msy = (d * a4.y * a4.y + 2.0f * a4.y * sy + qy) * inv;
        float msz = (d * a4.z * a4.z + 2.0f * a4.z * sz + qz) * inv;
        float msw = (d * a4.w * a4.w + 2.0f * a4.w * sw_ + qw) * inv;
        float4 mean4 = make_float4(mex, mey, mez, mew);
        float4 sd4 = make_float4(sqrtf(fmaxf(msx - mex * mex, 0.0f) + EPSV),
                                 sqrtf(fmaxf(msy - mey * mey, 0.0f) + EPSV),
                                 sqrtf(fmaxf(msz - mez * mez, 0.0f) + EPSV),
                                 sqrtf(fmaxf(msw - mew * mew, 0.0f) + EPSV));
        bool has = deg > 0;
        float4 mnv4 = has ? make_float4(a4.x + mnx, a4.y + mny, a4.z + mnz, a4.w + mnw)
                          : make_float4(0, 0, 0, 0);
        float4 mxv4 = has ? make_float4(a4.x + mxx, a4.y + mxy, a4.z + mxz, a4.w + mxw)
                          : make_float4(0, 0, 0, 0);
        int j0 = 4 * lane;
        int t = j0 / H, f = j0 - t * H;
        float* bb = base + (size_t)n * BASE_W + t * 160 + f;
        *(float4*)(bb)       = mean4;
        *(float4*)(bb + 40)  = mnv4;
        *(float4*)(bb + 80)  = mxv4;
        *(float4*)(bb + 120) = sd4;
    }
}

// ---------- post einsum, t-split: 2 nodes/thread share LDS weight reads ----------
__global__ __launch_bounds__(256) void k_post(const float* __restrict__ h, const float* __restrict__ base,
                                              const float* __restrict__ amp, const float* __restrict__ att,
                                              const float* __restrict__ post_w, const float* __restrict__ post_b,
                                              float* __restrict__ cpre, int layer) {
    __shared__ float ws[FO * WS_PAD];
    int tid = threadIdx.x;
    int t = blockIdx.y;
    const float* pwsrc = post_w + (size_t)(layer * T + t) * 520 * FO;
    for (int i = tid; i < 520 * FO; i += 256) {
        int g = i >> 3, o = i & 7;
        ws[o * WS_PAD + g] = pwsrc[i];
    }
    __syncthreads();
    int slot = tid >> 3, o = tid & 7;          // slot 0..31 -> node pair
    int n0 = blockIdx.x * 64 + slot * 2;
    if (n0 >= NN) return;
    int n1 = n0 + 1;
    bool two = (n1 < NN);
    if (!two) n1 = n0;
    const float* wrow = ws + o * WS_PAD;
    float am0 = amp[n0], at0 = att[n0];
    float am1 = amp[n1], at1 = att[n1];
    float pb = post_b[(size_t)(layer * T + t) * FO + o];
    float acc0 = pb, acc1 = pb;
    const float4* hx0 = (const float4*)(h + (size_t)n0 * H);
    const float4* hx1 = (const float4*)(h + (size_t)n1 * H);
    #pragma unroll
    for (int g4 = 0; g4 < 10; g4++) {
        float4 wv = *(const float4*)(wrow + g4 * 4);
        float4 x0 = hx0[g4], x1 = hx1[g4];
        acc0 += x0.x * wv.x + x0.y * wv.y + x0.z * wv.z + x0.w * wv.w;
        acc1 += x1.x * wv.x + x1.y * wv.y + x1.z * wv.z + x1.w * wv.w;
    }
    const float4* b0 = (const float4*)(base + (size_t)n0 * BASE_W + t * 160);
    const float4* b1 = (const float4*)(base + (size_t)n1 * BASE_W + t * 160);
    #pragma unroll 8
    for (int g4 = 0; g4 < 40; g4++) {
        float4 wa = *(const float4*)(wrow + 40 + g4 * 4);
        float4 wb = *(const float4*)(wrow + 200 + g4 * 4);
        float4 wc = *(const float4*)(wrow + 360 + g4 * 4);
        float4 v0 = b0[g4], v1 = b1[g4];
        acc0 += v0.x * (wa.x + am0 * wb.x + at0 * wc.x)
              + v0.y * (wa.y + am0 * wb.y + at0 * wc.y)
              + v0.z * (wa.z + am0 * wb.z + at0 * wc.z)
              + v0.w * (wa.w + am0 * wb.w + at0 * wc.w);
        acc1 += v1.x * (wa.x + am1 * wb.x + at1 * wc.x)
              + v1.y * (wa.y + am1 * wb.y + at1 * wc.y)
              + v1.z * (wa.z + am1 * wb.z + at1 * wc.z)
              + v1.w * (wa.w + am1 * wb.w + at1 * wc.w);
    }
    cpre[(size_t)n0 * H + t * FO + o] = acc0;
    if (two) cpre[(size_t)n1 * H + t * FO + o] = acc1;
}

// ---------- fused lin + BN-stats ----------
__global__ __launch_bounds__(256) void k_linbn(const float* __restrict__ cpre, const float* __restrict__ lin_w,
                                               const float* __restrict__ lin_b, float* __restrict__ cbuf,
                                               float* __restrict__ bnsum, float* __restrict__ bnsq, int layer) {
    __shared__ float scp[240];
    __shared__ float red[80];
    int tid = threadIdx.x;
    int j = tid % H, nl = tid / H;
    const float* lw = lin_w + (size_t)layer * H * H;
    float wcol[H];
    #pragma unroll
    for (int k = 0; k < H; k++) wcol[k] = lw[k * H + j];
    float lb = lin_b[(size_t)layer * H + j];
    float lsum = 0.0f, lsq = 0.0f;
    for (int n0 = blockIdx.x * 6; n0 < NN; n0 += gridDim.x * 6) {
        int nn = NN - n0; if (nn > 6) nn = 6;
        if (tid < nn * H) scp[tid] = cpre[(size_t)n0 * H + tid];
        __syncthreads();
        if (nl < nn) {
            float acc = lb;
            #pragma unroll
            for (int k = 0; k < H; k++) acc += scp[nl * H + k] * wcol[k];
            cbuf[(size_t)(n0 + nl) * H + j] = acc;
            lsum += acc; lsq += acc * acc;
        }
        __syncthreads();
    }
    if (tid < 80) red[tid] = 0.0f;
    __syncthreads();
    if (nl < 6) { atomicAdd(&red[j], lsum); atomicAdd(&red[40 + j], lsq); }
    __syncthreads();
    if (tid < 40) atomicAdd(&bnsum[tid], red[tid]);
    else if (tid < 80) atomicAdd(&bnsq[tid - 40], red[tid]);
}

// ---------- final prep: fused BN(layer1)+residual in LDS, then P1/P2 (5 nodes/block) ----------
__global__ __launch_bounds__(256) void k_prep2(const float* __restrict__ h, const float* __restrict__ cbuf,
                                               const float* __restrict__ bnsum, const float* __restrict__ bnsq,
                                               const float* __restrict__ bng, const float* __restrict__ bnb,
                                               const float* __restrict__ w1,
                                               float* __restrict__ P1, float* __restrict__ P2) {
    __shared__ float sh[5 * H];
    int tid = threadIdx.x;
    int n0 = blockIdx.x * 5;                 // NN % 5 == 0
    if (tid < 5 * H) {
        int j = tid % H;
        float invN = 1.0f / (float)NN;
        float mu = bnsum[j] * invN;
        float var = bnsq[j] * invN - mu * mu;
        float inv = rsqrtf(var + EPSV);
        float cv = (cbuf[(size_t)n0 * H + tid] - mu) * inv * bng[j] + bnb[j];
        sh[tid] = (h[(size_t)n0 * H + tid] + fmaxf(cv, 0.0f)) * 0.5f;
    }
    __syncthreads();
    if (tid >= 250) return;
    int nl = tid / 50, o = tid - nl * 50;
    const float* hr = sh + nl * H;
    float a1 = 0.0f, a2 = 0.0f;
    #pragma unroll
    for (int f = 0; f < H; f++) {
        float v = fmaxf(hr[f], 0.0f);
        a1 += v * w1[f * 50 + o];
        a2 += v * w1[(H + f) * 50 + o];
    }
    P1[(size_t)(n0 + nl) * PSTR + o] = a1;
    P2[(size_t)(n0 + nl) * PSTR + o] = a2;
}

// ---------- final edge MLP: all weights via uniform scalar loads (no LDS) ----------
__global__ __launch_bounds__(256) void k_mlp(const float* __restrict__ ea_csr, const int* __restrict__ pdst,
                                             const float* __restrict__ P1, const float* __restrict__ P2,
                                             const float* __restrict__ W1e, const float* __restrict__ b1e,
                                             const float* __restrict__ w2, const float* __restrict__ b2,
                                             const float* __restrict__ w3, const float* __restrict__ b3,
                                             float* __restrict__ out) {
    int p = blockIdx.x * 256 + threadIdx.x;
    if (p >= NE) return;
    const float4* rec = (const float4*)ea_csr + (size_t)p * 3;
    float4 r0 = rec[0], r1 = rec[1], r2 = rec[2];
    int s = __float_as_int(r2.z), eid = __float_as_int(r2.w);
    int d = pdst[p];
    float ea[EFD] = {r0.x, r0.y, r0.z, r0.w, r1.x, r1.y, r1.z, r1.w, r2.x, r2.y};

    float z1[52];
    const float4* p1r = (const float4*)(P1 + (size_t)s * PSTR);
    const float4* p2r = (const float4*)(P2 + (size_t)d * PSTR);
    #pragma unroll
    for (int i = 0; i < 13; i++) {
        float4 a = p1r[i], b = p2r[i];
        z1[4 * i]     = a.x + b.x;
        z1[4 * i + 1] = a.y + b.y;
        z1[4 * i + 2] = a.z + b.z;
        z1[4 * i + 3] = a.w + b.w;
    }
    #pragma unroll
    for (int k = 0; k < 50; k++) z1[k] += b1e[k];              // uniform -> scalar
    #pragma unroll
    for (int m = 0; m < EFD; m++) {
        float v = ea[m];
        #pragma unroll
        for (int k = 0; k < 50; k++) z1[k] = fmaf(v, W1e[m * 50 + k], z1[k]);
    }
    float z2[25];
    #pragma unroll
    for (int o = 0; o < 25; o++) z2[o] = b2[o];
    #pragma unroll
    for (int k = 0; k < 50; k++) {
        float v = fmaxf(z1[k], 0.0f);
        #pragma unroll
        for (int o = 0; o < 25; o++) z2[o] = fmaf(v, w2[k * 25 + o], z2[o]);
    }
    float o0 = b3[0], o1 = b3[1];
    #pragma unroll
    for (int k = 0; k < 25; k++) {
        float v = fmaxf(z2[k], 0.0f);
        o0 = fmaf(v, w3[k * 2], o0);
        o1 = fmaf(v, w3[k * 2 + 1], o1);
    }
    *(float2*)(out + (size_t)eid * 2) = make_float2(o0, o1);
}

extern "C" void kernel_launch(void* const* d_in, const int* in_sizes, int n_in,
                              void* d_out, int out_size, void* d_ws, size_t ws_size,
                              hipStream_t stream) {
    const float* x         = (const float*)d_in[0];
    const float* edge_attr = (const float*)d_in[1];
    const int*   eidx      = (const int*)  d_in[2];
    const float* node_w    = (const float*)d_in[3];
    const float* node_b    = (const float*)d_in[4];
    const float* edge_w    = (const float*)d_in[5];
    const float* edge_b    = (const float*)d_in[6];
    const float* enc_w     = (const float*)d_in[7];
    const float* enc_b     = (const float*)d_in[8];
    const float* pre_w     = (const float*)d_in[9];
    const float* pre_b     = (const float*)d_in[10];
    const float* post_w    = (const float*)d_in[11];
    const float* post_b    = (const float*)d_in[12];
    const float* lin_w     = (const float*)d_in[13];
    const float* lin_b     = (const float*)d_in[14];
    const float* bn_g      = (const float*)d_in[15];
    const float* bn_b      = (const float*)d_in[16];
    const float* w1 = (const float*)d_in[17];
    const float* b1 = (const float*)d_in[18];
    const float* w2 = (const float*)d_in[19];
    const float* b2 = (const float*)d_in[20];
    const float* w3 = (const float*)d_in[21];
    const float* b3 = (const float*)d_in[22];
    const int* srcp = eidx;
    const int* dstp = eidx + NE;
    float* out = (float*)d_out;

    char* ws = (char*)d_ws;
    size_t off = 0;
    auto alloc = [&](size_t bytes) -> char* {
        char* p = ws + off;
        off += (bytes + 255) & ~(size_t)255;
        return p;
    };
    float* h      = (float*)alloc((size_t)NN * H * 4);
    float* Abuf   = (float*)alloc((size_t)NN * TF * 4);
    float* cbuf   = (float*)alloc((size_t)NN * H * 4);
    __hip_bfloat16* Bbf = (__hip_bfloat16*)alloc((size_t)NN * TF * 2 + 256);
    float* base   = (float*)alloc((size_t)NN * BASE_W * 4);
    float* cpre   = (float*)alloc((size_t)NN * H * 4);
    float* ea_csr = (float*)alloc((size_t)NE * REC * 4);
    int* pdst     = (int*)alloc((size_t)NE * 4);
    float* W3e    = (float*)alloc((size_t)EFD * TF * 4);
    float* dvecF  = (float*)alloc((size_t)TF * 4);
    __hip_bfloat16* Wcat = (__hip_bfloat16*)alloc((size_t)WCN * WCK * 2);
    float* P1     = (float*)alloc((size_t)NN * PSTR * 4);
    float* P2     = (float*)alloc((size_t)NN * PSTR * 4);
    float* W1e    = (float*)alloc((size_t)EFD * 50 * 4);
    float* b1e    = (float*)alloc((size_t)64 * 4);
    float* amp    = (float*)alloc((size_t)NN * 4);
    float* att    = (float*)alloc((size_t)NN * 4);
    int* offs     = (int*)alloc((size_t)(NN + 1) * 4);
    // ---- contiguous zero region: cnt, fill, avgs, bnz(2 layers) ----
    size_t zoff = off;
    int* cnt_i    = (int*)alloc((size_t)NN * 4);
    int* fill     = (int*)alloc((size_t)NN * 4);
    float* avgs   = (float*)alloc(256);
    float* bnz    = (float*)alloc(1024);   // layer l: bnz + l*128 floats (sum 40 | sq 40)
    size_t zsize = off - zoff;
    if (off > ws_size) return;

    hipMemsetAsync(cnt_i, 0, zsize, stream);

    k_deg<<<(NE + 255) / 256, 256, 0, stream>>>(dstp, cnt_i);
    k_avglog<<<64, 256, 0, stream>>>(cnt_i, avgs);
    k_node<<<(NN * H + 255) / 256, 256, 0, stream>>>(x, node_w, node_b, h, cnt_i, avgs, amp, att);
    k_scan<<<1, 1024, 0, stream>>>(cnt_i, offs);
    k_scatter<<<(NE + 255) / 256, 256, 0, stream>>>(srcp, dstp, edge_attr, offs, fill, ea_csr, pdst);

    int prep1_grid = (EFD * TF + WCN * WCK + EFD * 50 + 255) / 256;
    for (int layer = 0; layer < LAYERS; layer++) {
        float* bnzL = bnz + layer * 128;
        k_prep1<<<prep1_grid, 256, 0, stream>>>(
            enc_w, enc_b, edge_w, edge_b, pre_w, pre_b, w1, b1,
            W3e, dvecF, Wcat, W1e, b1e, layer);
        float* bnzP = bnz + (layer - 1) * 128;
        k_abm<<<(NN + 63) / 64, 256, 0, stream>>>(
            h, cbuf, (layer > 0) ? bnzP : bnz, (layer > 0) ? bnzP + 40 : bnz,
            bn_g + (size_t)(layer > 0 ? layer - 1 : 0) * H,
            bn_b + (size_t)(layer > 0 ? layer - 1 : 0) * H,
            (layer > 0) ? 1 : 0, Wcat, Abuf, Bbf);
        k_agg<<<NN / 4, 256, 0, stream>>>(ea_csr, Bbf, Abuf, W3e, dvecF, cnt_i, offs, base);
        k_post<<<dim3((NN + 63) / 64, T), 256, 0, stream>>>(h, base, amp, att, post_w, post_b, cpre, layer);
        k_linbn<<<1024, 256, 0, stream>>>(cpre, lin_w, lin_b, cbuf, bnzL, bnzL + 40, layer);
    }
    k_prep2<<<NN / 5, 256, 0, stream>>>(h, cbuf, bnz + 128, bnz + 168,
                                        bn_g + H, bn_b + H, w1, P1, P2);
    k_mlp<<<(NE + 255) / 256, 256, 0, stream>>>(ea_csr, pdst, P1, P2, W1e, b1e, w2, b2, w3, b3, out);
}